// Round 17
// baseline (140.341 us; speedup 1.0000x reference)
//
#include <hip/hip_runtime.h>

typedef short bf16x8 __attribute__((ext_vector_type(8)));
typedef float f32x4 __attribute__((ext_vector_type(4)));
typedef unsigned int u32x4 __attribute__((ext_vector_type(4)));

#define QSCALE 0.18033688011112042f  // 0.125 * log2(e); attention works in log2 units

__device__ __forceinline__ unsigned short f2bf(float x) {
  unsigned int u = __float_as_uint(x);
  u = (u + 0x7FFFu + ((u >> 16) & 1u)) >> 16;
  return (unsigned short)u;
}

// round-to-nearest(half-up) pack of two f32 into {lo=bf16(a), hi=bf16(b)}
__device__ __forceinline__ unsigned pack_rn(float a, float b) {
  unsigned au = __float_as_uint(a) + 0x8000u;
  unsigned bu = __float_as_uint(b) + 0x8000u;
  return (bu & 0xFFFF0000u) | (au >> 16);
}

__device__ __forceinline__ void async16(const void* g, void* l) {
  typedef const __attribute__((address_space(1))) unsigned int* gp_t;
  typedef __attribute__((address_space(3))) unsigned int* lp_t;
  __builtin_amdgcn_global_load_lds((gp_t)g, (lp_t)l, 16, 0, 0);
}

union frag_u { bf16x8 f; unsigned int u[4]; };

// one launch for the 3 weight tensors (qw | kvw | pw), float4 units
__global__ void cast_w3(const float* __restrict__ qw, const float* __restrict__ kvw,
                        const float* __restrict__ pw, unsigned short* __restrict__ qwo,
                        unsigned short* __restrict__ kvwo, unsigned short* __restrict__ pwo) {
  int i = blockIdx.x * 256 + threadIdx.x;   // 0 .. 557055
  const float* src; unsigned short* dst; int j;
  if (i < 262144)      { src = qw;  dst = qwo;  j = i; }
  else if (i < 294912) { src = kvw; dst = kvwo; j = i - 262144; }
  else                 { src = pw;  dst = pwo;  j = i - 294912; }
  float4 v = ((const float4*)src)[j];
  ushort4 o;
  o.x = f2bf(v.x); o.y = f2bf(v.y); o.z = f2bf(v.z); o.w = f2bf(v.w);
  ((ushort4*)dst)[j] = o;
}

// ============ 256x256 GEMM, C = A * B^T (R8-verified schedule) ============
// MODE 0: bf16 out (scaled by oscale). MODE 1: f32 out + bias.
template<int MODE>
__global__ __launch_bounds__(512, 2) void gemm256(
    const unsigned short* __restrict__ A,
    const unsigned short* __restrict__ Bw,
    unsigned short* __restrict__ Cbf,
    float* __restrict__ Cf,
    const float* __restrict__ bias,
    const float oscale,
    int M, int N, int K)
{
  __shared__ unsigned short S[65536];
  const int t = threadIdx.x;
  const int lane = t & 63, wave = t >> 6;
  const int g = lane >> 4, r = lane & 15;
  const int wm = wave >> 2, wn = wave & 3;

  const int nby = N >> 8;
  const int cpx = gridDim.x >> 3;
  const int bid = blockIdx.x;
  const int swz = (bid & 7) * cpx + (bid >> 3);
  const long row0 = (long)(swz / nby) * 256;
  const long col0 = (long)(swz % nby) * 256;

  const int NT = K >> 6;

  auto stage = [&](const unsigned short* gsrc, long grow0, int kcol0, int region) {
#pragma unroll
    for (int i = 0; i < 2; ++i) {
      int o = (i * 512 + t) << 4;
      int row = o >> 7;
      int scol = (o & 127) ^ ((row & 7) << 4);
      async16(gsrc + (grow0 + row) * K + kcol0 + (scol >> 1),
              (char*)S + region + i * 8192 + wave * 1024);
    }
  };
  auto ldA = [&](int bo, int ar, int ks) {
    return *(const bf16x8*)((const char*)S + bo + ar * 128 +
                            ((ks * 64 + g * 16) ^ ((ar & 7) << 4)));
  };
  auto ldB = [&](int bo, int br, int ks) {
    return *(const bf16x8*)((const char*)S + bo + 32768 + br * 128 +
                            ((ks * 64 + g * 16) ^ ((br & 7) << 4)));
  };

  f32x4 acc[8][4] = {};
  bf16x8 aF[4][2], b01[2][2], b23[2][2];

  stage(A,  row0,       0, 0);
  stage(A,  row0 + 128, 0, 16384);
  stage(Bw, col0,       0, 32768);
  stage(Bw, col0 + 128, 0, 32768 + 16384);
  if (NT > 1) {
    stage(Bw, col0,       64, 65536 + 32768);
    stage(Bw, col0 + 128, 64, 65536 + 32768 + 16384);
    asm volatile("s_waitcnt vmcnt(4)" ::: "memory");
  } else {
    asm volatile("s_waitcnt vmcnt(0)" ::: "memory");
  }
  __builtin_amdgcn_s_barrier();

  for (int kt = 0; kt < NT; ++kt) {
    const int bo = (kt & 1) << 16;
    // P0: read A(mf0-3)+B(nf0-1); stage A-half0(t+1)
#pragma unroll
    for (int mf = 0; mf < 4; ++mf) {
      int ar = wm * 128 + mf * 16 + r;
      aF[mf][0] = ldA(bo, ar, 0); aF[mf][1] = ldA(bo, ar, 1);
    }
#pragma unroll
    for (int nf = 0; nf < 2; ++nf) {
      int br = wn * 64 + nf * 16 + r;
      b01[nf][0] = ldB(bo, br, 0); b01[nf][1] = ldB(bo, br, 1);
    }
    if (kt + 1 < NT) stage(A, row0, (kt + 1) * 64, bo ^ 65536);
    __builtin_amdgcn_s_barrier();
    __builtin_amdgcn_s_setprio(1);
#pragma unroll
    for (int mf = 0; mf < 4; ++mf)
#pragma unroll
      for (int nf = 0; nf < 2; ++nf) {
        acc[mf][nf] = __builtin_amdgcn_mfma_f32_16x16x32_bf16(aF[mf][0], b01[nf][0], acc[mf][nf], 0, 0, 0);
        acc[mf][nf] = __builtin_amdgcn_mfma_f32_16x16x32_bf16(aF[mf][1], b01[nf][1], acc[mf][nf], 0, 0, 0);
      }
    __builtin_amdgcn_s_setprio(0);
    // P1: read B(nf2-3); stage A-half1(t+1)
#pragma unroll
    for (int nf = 0; nf < 2; ++nf) {
      int br = wn * 64 + (nf + 2) * 16 + r;
      b23[nf][0] = ldB(bo, br, 0); b23[nf][1] = ldB(bo, br, 1);
    }
    if (kt + 1 < NT) stage(A, row0 + 128, (kt + 1) * 64, (bo ^ 65536) + 16384);
    __builtin_amdgcn_s_barrier();
    __builtin_amdgcn_s_setprio(1);
#pragma unroll
    for (int mf = 0; mf < 4; ++mf)
#pragma unroll
      for (int nf = 0; nf < 2; ++nf) {
        acc[mf][nf + 2] = __builtin_amdgcn_mfma_f32_16x16x32_bf16(aF[mf][0], b23[nf][0], acc[mf][nf + 2], 0, 0, 0);
        acc[mf][nf + 2] = __builtin_amdgcn_mfma_f32_16x16x32_bf16(aF[mf][1], b23[nf][1], acc[mf][nf + 2], 0, 0, 0);
      }
    __builtin_amdgcn_s_setprio(0);
    // P2: read A(mf4-7); stage B-half0(t+2)
#pragma unroll
    for (int mf = 0; mf < 4; ++mf) {
      int ar = wm * 128 + (mf + 4) * 16 + r;
      aF[mf][0] = ldA(bo, ar, 0); aF[mf][1] = ldA(bo, ar, 1);
    }
    if (kt + 2 < NT) stage(Bw, col0, (kt + 2) * 64, bo + 32768);
    __builtin_amdgcn_s_barrier();
    __builtin_amdgcn_s_setprio(1);
#pragma unroll
    for (int mf = 0; mf < 4; ++mf)
#pragma unroll
      for (int nf = 0; nf < 2; ++nf) {
        acc[mf + 4][nf + 2] = __builtin_amdgcn_mfma_f32_16x16x32_bf16(aF[mf][0], b23[nf][0], acc[mf + 4][nf + 2], 0, 0, 0);
        acc[mf + 4][nf + 2] = __builtin_amdgcn_mfma_f32_16x16x32_bf16(aF[mf][1], b23[nf][1], acc[mf + 4][nf + 2], 0, 0, 0);
      }
    __builtin_amdgcn_s_setprio(0);
    // P4: stage B-half1(t+2); MFMA (mf4-7 x nf0-1); counted end-of-tile vmcnt
    if (kt + 2 < NT) stage(Bw, col0 + 128, (kt + 2) * 64, bo + 32768 + 16384);
    __builtin_amdgcn_s_setprio(1);
#pragma unroll
    for (int mf = 0; mf < 4; ++mf)
#pragma unroll
      for (int nf = 0; nf < 2; ++nf) {
        acc[mf + 4][nf] = __builtin_amdgcn_mfma_f32_16x16x32_bf16(aF[mf][0], b01[nf][0], acc[mf + 4][nf], 0, 0, 0);
        acc[mf + 4][nf] = __builtin_amdgcn_mfma_f32_16x16x32_bf16(aF[mf][1], b01[nf][1], acc[mf + 4][nf], 0, 0, 0);
      }
    __builtin_amdgcn_s_setprio(0);
    if (kt < NT - 2)      asm volatile("s_waitcnt vmcnt(4)" ::: "memory");
    else if (kt < NT - 1) asm volatile("s_waitcnt vmcnt(0)" ::: "memory");
    if (kt < NT - 1) __builtin_amdgcn_s_barrier();
  }

  if (MODE == 0) {
#pragma unroll
    for (int mf = 0; mf < 8; ++mf)
#pragma unroll
      for (int nf = 0; nf < 4; ++nf) {
        long rr = row0 + wm * 128 + mf * 16 + g * 4;
        long cc = col0 + wn * 64 + nf * 16 + r;
#pragma unroll
        for (int i = 0; i < 4; ++i)
          Cbf[(rr + i) * N + cc] = f2bf(acc[mf][nf][i] * oscale);
      }
  } else {
#pragma unroll
    for (int mf = 0; mf < 8; ++mf)
#pragma unroll
      for (int nf = 0; nf < 4; ++nf) {
        long rr = row0 + wm * 128 + mf * 16 + g * 4;
        long cc = col0 + wn * 64 + nf * 16 + r;
        float bb = bias[cc];
#pragma unroll
        for (int i = 0; i < 4; ++i)
          Cf[(rr + i) * N + cc] = acc[mf][nf][i] + bb;
      }
  }
}

// ---- kv GEMM + x cast fused: BM=32, 512 blocks (2/CU, 8 waves/CU) ----
__global__ __launch_bounds__(256) void gemm_kv_cast(
    const float* __restrict__ x,            // [16384][1024] f32
    const unsigned short* __restrict__ Bw,  // kvw_bf [128][1024]
    unsigned short* __restrict__ xbf,       // [16384][1024] bf16 out
    unsigned short* __restrict__ Kout,      // [16384][64]
    unsigned short* __restrict__ VTout)     // [64][64][256]
{
  __shared__ unsigned short As[32 * 64];    // 4KB, swizzled
  __shared__ unsigned short Bs[128 * 64];   // 16KB, swizzled
  const int t = threadIdx.x;
  const int lane = t & 63, wave = t >> 6;
  const int g = lane >> 4, r = lane & 15;
  const int wr = wave >> 1, wc = wave & 1;  // wr: 16-row half; wc: K vs V
  const long row0 = (long)blockIdx.x * 32;
  const int arow = t >> 3, aq = t & 7;      // 8 lanes per row: 2 float4 each

  f32x4 acc[4] = {};

  for (int kt = 0; kt < 1024; kt += 64) {
    __syncthreads();
    const float4* src = (const float4*)(x + (row0 + arow) * 1024 + kt + aq * 8);
    float4 av0 = src[0];
    float4 av1 = src[1];
#pragma unroll
    for (int i = 0; i < 4; ++i) {
      int o = (i * 256 + t) << 4;
      int brow = o >> 7;
      int scol = (o & 127) ^ ((brow & 7) << 4);
      async16(Bw + brow * 1024 + kt + (scol >> 1), (char*)Bs + i * 4096 + wave * 1024);
    }
    u32x4 u;
    u[0] = pack_rn(av0.x, av0.y); u[1] = pack_rn(av0.z, av0.w);
    u[2] = pack_rn(av1.x, av1.y); u[3] = pack_rn(av1.z, av1.w);
    *(u32x4*)((char*)As + arow * 128 + ((aq * 16) ^ ((arow & 7) << 4))) = u;
    *(u32x4*)(xbf + (row0 + arow) * 1024 + kt + aq * 8) = u;
    __syncthreads();
#pragma unroll
    for (int ks = 0; ks < 2; ++ks) {
      int ar = wr * 16 + r;
      bf16x8 af = *(const bf16x8*)((const char*)As + ar * 128 + ((ks * 64 + g * 16) ^ ((ar & 7) << 4)));
#pragma unroll
      for (int cf = 0; cf < 4; ++cf) {
        int br = wc * 64 + cf * 16 + r;
        bf16x8 bfr = *(const bf16x8*)((const char*)Bs + br * 128 + ((ks * 64 + g * 16) ^ ((br & 7) << 4)));
        acc[cf] = __builtin_amdgcn_mfma_f32_16x16x32_bf16(af, bfr, acc[cf], 0, 0, 0);
      }
    }
  }

  if (wc == 0) {  // K part: cols 0..63
#pragma unroll
    for (int cf = 0; cf < 4; ++cf) {
      long rr = row0 + wr * 16 + g * 4;
      int cc = cf * 16 + r;
#pragma unroll
      for (int i = 0; i < 4; ++i)
        Kout[(rr + i) * 64 + cc] = f2bf(acc[cf][i]);
    }
  } else {        // V part -> transposed [w16][hd][kpos]
#pragma unroll
    for (int cf = 0; cf < 4; ++cf) {
      long tok = row0 + wr * 16 + g * 4;
      long w16 = tok >> 8;
      int kp = (int)(tok & 255);
      int hd = cf * 16 + r;
      ushort4 pk;
      pk.x = f2bf(acc[cf][0]); pk.y = f2bf(acc[cf][1]);
      pk.z = f2bf(acc[cf][2]); pk.w = f2bf(acc[cf][3]);
      *(ushort4*)(VTout + (w16 * 64 + hd) * 256 + kp) = pk;
    }
  }
}

// ---------------- windowed attention: LDS-free (K/V are XCD-L2-resident) ----------------
// XCD-local decode: hp = blk>>6, w16 = blk&63 -> same-window blocks share an XCD.
// No __shared__, no barriers: waves fully independent (setprio regime).
__global__ __launch_bounds__(512, 2) void attn_win(
    const unsigned short* __restrict__ qb,   // [16384][1024], pre-scaled
    const unsigned short* __restrict__ kb,   // [16384][64]
    const unsigned short* __restrict__ vt,   // [64 w16][64 hd][256 kpos]
    unsigned short* __restrict__ ao)         // [16384][1024]
{
  const int blk = blockIdx.x;
  const int hp = blk >> 6;
  const int w16 = blk & 63;
  const long tok0 = (long)w16 * 256;
  const int t = threadIdx.x;
  const int lane = t & 63, wave = t >> 6;
  const int g = lane >> 4, r = lane & 15;
  const int h = hp * 2 + (wave >> 2);
  const int qw = wave & 3;

  const unsigned short* kbase = kb + tok0 * 64;
  const unsigned short* vbase = vt + (long)w16 * (64 * 256);

  bf16x8 qf[4][2];
#pragma unroll
  for (int cq = 0; cq < 4; ++cq)
#pragma unroll
    for (int kh = 0; kh < 2; ++kh)
      qf[cq][kh] = *(const bf16x8*)(qb + (tok0 + qw * 64 + cq * 16 + r) * 1024 + h * 64 + kh * 32 + g * 8);

  f32x4 O[4][4] = {};
  float sp[4] = {0.f, 0.f, 0.f, 0.f};
  const int rsub = 8 * (r >> 2) + (r & 3);   // permuted K-row gather (P-layout trick)

#pragma unroll
  for (int kc = 0; kc < 8; ++kc) {
    f32x4 sc[2][4] = {};
#pragma unroll
    for (int kr = 0; kr < 2; ++kr) {
      int kp = kc * 32 + kr * 4 + rsub;
      bf16x8 kf0 = *(const bf16x8*)(kbase + kp * 64 + g * 8);
      bf16x8 kf1 = *(const bf16x8*)(kbase + kp * 64 + 32 + g * 8);
      __builtin_amdgcn_s_setprio(1);
#pragma unroll
      for (int cq = 0; cq < 4; ++cq) {
        sc[kr][cq] = __builtin_amdgcn_mfma_f32_16x16x32_bf16(kf0, qf[cq][0], sc[kr][cq], 0, 0, 0);
        sc[kr][cq] = __builtin_amdgcn_mfma_f32_16x16x32_bf16(kf1, qf[cq][1], sc[kr][cq], 0, 0, 0);
      }
      __builtin_amdgcn_s_setprio(0);
    }
    bf16x8 vf[4];
#pragma unroll
    for (int ch = 0; ch < 4; ++ch)
      vf[ch] = *(const bf16x8*)(vbase + (ch * 16 + r) * 256 + kc * 32 + g * 8);
#pragma unroll
    for (int cq = 0; cq < 4; ++cq) {
#pragma unroll
      for (int kr = 0; kr < 2; ++kr)
#pragma unroll
        for (int i = 0; i < 4; ++i)
          sc[kr][cq][i] = __builtin_amdgcn_exp2f(sc[kr][cq][i]);
      sp[cq] += ((sc[0][cq][0] + sc[0][cq][1]) + (sc[0][cq][2] + sc[0][cq][3])) +
                ((sc[1][cq][0] + sc[1][cq][1]) + (sc[1][cq][2] + sc[1][cq][3]));
    }
#pragma unroll
    for (int rq = 0; rq < 4; ++rq) {
      frag_u pa;
      pa.u[0] = pack_rn(sc[0][rq][0], sc[0][rq][1]);
      pa.u[1] = pack_rn(sc[0][rq][2], sc[0][rq][3]);
      pa.u[2] = pack_rn(sc[1][rq][0], sc[1][rq][1]);
      pa.u[3] = pack_rn(sc[1][rq][2], sc[1][rq][3]);
      __builtin_amdgcn_s_setprio(1);
#pragma unroll
      for (int ch = 0; ch < 4; ++ch)
        O[rq][ch] = __builtin_amdgcn_mfma_f32_16x16x32_bf16(pa.f, vf[ch], O[rq][ch], 0, 0, 0);
      __builtin_amdgcn_s_setprio(0);
    }
  }
  float inv[4];
#pragma unroll
  for (int cq = 0; cq < 4; ++cq) {
    float s = sp[cq];
    s += __shfl_xor(s, 16);
    s += __shfl_xor(s, 32);
    inv[cq] = 1.0f / s;
  }
#pragma unroll
  for (int rq = 0; rq < 4; ++rq)
#pragma unroll
    for (int i = 0; i < 4; ++i) {
      float w = __shfl(inv[rq], g * 4 + i);
      long tokr = tok0 + qw * 64 + rq * 16 + g * 4 + i;
#pragma unroll
      for (int ch = 0; ch < 4; ++ch)
        ao[tokr * 1024 + h * 64 + ch * 16 + r] = f2bf(O[rq][ch][i] * w);
    }
}

// ---------------- launch ----------------
extern "C" void kernel_launch(void* const* d_in, const int* in_sizes, int n_in,
                              void* d_out, int out_size, void* d_ws, size_t ws_size,
                              hipStream_t stream) {
  const float* x      = (const float*)d_in[0];
  const float* q_w    = (const float*)d_in[1];
  const float* kv_w   = (const float*)d_in[2];
  const float* proj_w = (const float*)d_in[3];
  const float* proj_b = (const float*)d_in[4];

  char* ws = (char*)d_ws;
  unsigned short* x_bf   = (unsigned short*)(ws + 0);
  unsigned short* q_bf   = (unsigned short*)(ws + 33554432);
  unsigned short* ao_bf  = (unsigned short*)(ws + 67108864);
  unsigned short* qw_bf  = (unsigned short*)(ws + 100663296);
  unsigned short* pw_bf  = (unsigned short*)(ws + 102760448);
  unsigned short* kvw_bf = (unsigned short*)(ws + 104857600);
  unsigned short* k_bf   = (unsigned short*)(ws + 105119744);
  unsigned short* vt_bf  = (unsigned short*)(ws + 107216896);
  if (ws_size < 109314048) return;

  cast_w3<<<2176, 256, 0, stream>>>(q_w, kv_w, proj_w, qw_bf, kvw_bf, pw_bf);
  gemm_kv_cast<<<512, 256, 0, stream>>>(x, kvw_bf, x_bf, k_bf, vt_bf);

  gemm256<0><<<256, 512, 0, stream>>>(x_bf, qw_bf, q_bf, nullptr, nullptr, QSCALE, 16384, 1024, 1024);
  attn_win<<<512, 512, 0, stream>>>(q_bf, k_bf, vt_bf, ao_bf);
  gemm256<1><<<256, 512, 0, stream>>>(ao_bf, pw_bf, nullptr, (float*)d_out, proj_b, 1.0f, 16384, 1024, 1024);
}

// Round 18
// 125.230 us; speedup vs baseline: 1.1207x; 1.1207x over previous
//
#include <hip/hip_runtime.h>

typedef short bf16x8 __attribute__((ext_vector_type(8)));
typedef float f32x4 __attribute__((ext_vector_type(4)));
typedef unsigned int u32x4 __attribute__((ext_vector_type(4)));

#define QSCALE 0.18033688011112042f  // 0.125 * log2(e); attention works in log2 units

__device__ __forceinline__ unsigned short f2bf(float x) {
  unsigned int u = __float_as_uint(x);
  u = (u + 0x7FFFu + ((u >> 16) & 1u)) >> 16;
  return (unsigned short)u;
}

// round-to-nearest(half-up) pack of two f32 into {lo=bf16(a), hi=bf16(b)}
__device__ __forceinline__ unsigned pack_rn(float a, float b) {
  unsigned au = __float_as_uint(a) + 0x8000u;
  unsigned bu = __float_as_uint(b) + 0x8000u;
  return (bu & 0xFFFF0000u) | (au >> 16);
}

__device__ __forceinline__ void async16(const void* g, void* l) {
  typedef const __attribute__((address_space(1))) unsigned int* gp_t;
  typedef __attribute__((address_space(3))) unsigned int* lp_t;
  __builtin_amdgcn_global_load_lds((gp_t)g, (lp_t)l, 16, 0, 0);
}

union frag_u { bf16x8 f; unsigned int u[4]; };

// one launch for the 3 weight tensors (qw | kvw | pw), float4 units
__global__ void cast_w3(const float* __restrict__ qw, const float* __restrict__ kvw,
                        const float* __restrict__ pw, unsigned short* __restrict__ qwo,
                        unsigned short* __restrict__ kvwo, unsigned short* __restrict__ pwo) {
  int i = blockIdx.x * 256 + threadIdx.x;   // 0 .. 557055
  const float* src; unsigned short* dst; int j;
  if (i < 262144)      { src = qw;  dst = qwo;  j = i; }
  else if (i < 294912) { src = kvw; dst = kvwo; j = i - 262144; }
  else                 { src = pw;  dst = pwo;  j = i - 294912; }
  float4 v = ((const float4*)src)[j];
  ushort4 o;
  o.x = f2bf(v.x); o.y = f2bf(v.y); o.z = f2bf(v.z); o.w = f2bf(v.w);
  ((ushort4*)dst)[j] = o;
}

// ============ 256x256 GEMM, C = A * B^T (R8-verified schedule) ============
// MODE 0: bf16 out (scaled by oscale). MODE 1: f32 out + bias.
template<int MODE>
__global__ __launch_bounds__(512, 2) void gemm256(
    const unsigned short* __restrict__ A,
    const unsigned short* __restrict__ Bw,
    unsigned short* __restrict__ Cbf,
    float* __restrict__ Cf,
    const float* __restrict__ bias,
    const float oscale,
    int M, int N, int K)
{
  __shared__ unsigned short S[65536];
  const int t = threadIdx.x;
  const int lane = t & 63, wave = t >> 6;
  const int g = lane >> 4, r = lane & 15;
  const int wm = wave >> 2, wn = wave & 3;

  const int nby = N >> 8;
  const int cpx = gridDim.x >> 3;
  const int bid = blockIdx.x;
  const int swz = (bid & 7) * cpx + (bid >> 3);
  const long row0 = (long)(swz / nby) * 256;
  const long col0 = (long)(swz % nby) * 256;

  const int NT = K >> 6;

  auto stage = [&](const unsigned short* gsrc, long grow0, int kcol0, int region) {
#pragma unroll
    for (int i = 0; i < 2; ++i) {
      int o = (i * 512 + t) << 4;
      int row = o >> 7;
      int scol = (o & 127) ^ ((row & 7) << 4);
      async16(gsrc + (grow0 + row) * K + kcol0 + (scol >> 1),
              (char*)S + region + i * 8192 + wave * 1024);
    }
  };
  auto ldA = [&](int bo, int ar, int ks) {
    return *(const bf16x8*)((const char*)S + bo + ar * 128 +
                            ((ks * 64 + g * 16) ^ ((ar & 7) << 4)));
  };
  auto ldB = [&](int bo, int br, int ks) {
    return *(const bf16x8*)((const char*)S + bo + 32768 + br * 128 +
                            ((ks * 64 + g * 16) ^ ((br & 7) << 4)));
  };

  f32x4 acc[8][4] = {};
  bf16x8 aF[4][2], b01[2][2], b23[2][2];

  stage(A,  row0,       0, 0);
  stage(A,  row0 + 128, 0, 16384);
  stage(Bw, col0,       0, 32768);
  stage(Bw, col0 + 128, 0, 32768 + 16384);
  if (NT > 1) {
    stage(Bw, col0,       64, 65536 + 32768);
    stage(Bw, col0 + 128, 64, 65536 + 32768 + 16384);
    asm volatile("s_waitcnt vmcnt(4)" ::: "memory");
  } else {
    asm volatile("s_waitcnt vmcnt(0)" ::: "memory");
  }
  __builtin_amdgcn_s_barrier();

  for (int kt = 0; kt < NT; ++kt) {
    const int bo = (kt & 1) << 16;
    // P0: read A(mf0-3)+B(nf0-1); stage A-half0(t+1)
#pragma unroll
    for (int mf = 0; mf < 4; ++mf) {
      int ar = wm * 128 + mf * 16 + r;
      aF[mf][0] = ldA(bo, ar, 0); aF[mf][1] = ldA(bo, ar, 1);
    }
#pragma unroll
    for (int nf = 0; nf < 2; ++nf) {
      int br = wn * 64 + nf * 16 + r;
      b01[nf][0] = ldB(bo, br, 0); b01[nf][1] = ldB(bo, br, 1);
    }
    if (kt + 1 < NT) stage(A, row0, (kt + 1) * 64, bo ^ 65536);
    __builtin_amdgcn_s_barrier();
    __builtin_amdgcn_s_setprio(1);
#pragma unroll
    for (int mf = 0; mf < 4; ++mf)
#pragma unroll
      for (int nf = 0; nf < 2; ++nf) {
        acc[mf][nf] = __builtin_amdgcn_mfma_f32_16x16x32_bf16(aF[mf][0], b01[nf][0], acc[mf][nf], 0, 0, 0);
        acc[mf][nf] = __builtin_amdgcn_mfma_f32_16x16x32_bf16(aF[mf][1], b01[nf][1], acc[mf][nf], 0, 0, 0);
      }
    __builtin_amdgcn_s_setprio(0);
    // P1: read B(nf2-3); stage A-half1(t+1)
#pragma unroll
    for (int nf = 0; nf < 2; ++nf) {
      int br = wn * 64 + (nf + 2) * 16 + r;
      b23[nf][0] = ldB(bo, br, 0); b23[nf][1] = ldB(bo, br, 1);
    }
    if (kt + 1 < NT) stage(A, row0 + 128, (kt + 1) * 64, (bo ^ 65536) + 16384);
    __builtin_amdgcn_s_barrier();
    __builtin_amdgcn_s_setprio(1);
#pragma unroll
    for (int mf = 0; mf < 4; ++mf)
#pragma unroll
      for (int nf = 0; nf < 2; ++nf) {
        acc[mf][nf + 2] = __builtin_amdgcn_mfma_f32_16x16x32_bf16(aF[mf][0], b23[nf][0], acc[mf][nf + 2], 0, 0, 0);
        acc[mf][nf + 2] = __builtin_amdgcn_mfma_f32_16x16x32_bf16(aF[mf][1], b23[nf][1], acc[mf][nf + 2], 0, 0, 0);
      }
    __builtin_amdgcn_s_setprio(0);
    // P2: read A(mf4-7); stage B-half0(t+2)
#pragma unroll
    for (int mf = 0; mf < 4; ++mf) {
      int ar = wm * 128 + (mf + 4) * 16 + r;
      aF[mf][0] = ldA(bo, ar, 0); aF[mf][1] = ldA(bo, ar, 1);
    }
    if (kt + 2 < NT) stage(Bw, col0, (kt + 2) * 64, bo + 32768);
    __builtin_amdgcn_s_barrier();
    __builtin_amdgcn_s_setprio(1);
#pragma unroll
    for (int mf = 0; mf < 4; ++mf)
#pragma unroll
      for (int nf = 0; nf < 2; ++nf) {
        acc[mf + 4][nf + 2] = __builtin_amdgcn_mfma_f32_16x16x32_bf16(aF[mf][0], b23[nf][0], acc[mf + 4][nf + 2], 0, 0, 0);
        acc[mf + 4][nf + 2] = __builtin_amdgcn_mfma_f32_16x16x32_bf16(aF[mf][1], b23[nf][1], acc[mf + 4][nf + 2], 0, 0, 0);
      }
    __builtin_amdgcn_s_setprio(0);
    // P4: stage B-half1(t+2); MFMA (mf4-7 x nf0-1); counted end-of-tile vmcnt
    if (kt + 2 < NT) stage(Bw, col0 + 128, (kt + 2) * 64, bo + 32768 + 16384);
    __builtin_amdgcn_s_setprio(1);
#pragma unroll
    for (int mf = 0; mf < 4; ++mf)
#pragma unroll
      for (int nf = 0; nf < 2; ++nf) {
        acc[mf + 4][nf] = __builtin_amdgcn_mfma_f32_16x16x32_bf16(aF[mf][0], b01[nf][0], acc[mf + 4][nf], 0, 0, 0);
        acc[mf + 4][nf] = __builtin_amdgcn_mfma_f32_16x16x32_bf16(aF[mf][1], b01[nf][1], acc[mf + 4][nf], 0, 0, 0);
      }
    __builtin_amdgcn_s_setprio(0);
    if (kt < NT - 2)      asm volatile("s_waitcnt vmcnt(4)" ::: "memory");
    else if (kt < NT - 1) asm volatile("s_waitcnt vmcnt(0)" ::: "memory");
    if (kt < NT - 1) __builtin_amdgcn_s_barrier();
  }

  if (MODE == 0) {
#pragma unroll
    for (int mf = 0; mf < 8; ++mf)
#pragma unroll
      for (int nf = 0; nf < 4; ++nf) {
        long rr = row0 + wm * 128 + mf * 16 + g * 4;
        long cc = col0 + wn * 64 + nf * 16 + r;
#pragma unroll
        for (int i = 0; i < 4; ++i)
          Cbf[(rr + i) * N + cc] = f2bf(acc[mf][nf][i] * oscale);
      }
  } else {
#pragma unroll
    for (int mf = 0; mf < 8; ++mf)
#pragma unroll
      for (int nf = 0; nf < 4; ++nf) {
        long rr = row0 + wm * 128 + mf * 16 + g * 4;
        long cc = col0 + wn * 64 + nf * 16 + r;
        float bb = bias[cc];
#pragma unroll
        for (int i = 0; i < 4; ++i)
          Cf[(rr + i) * N + cc] = acc[mf][nf][i] + bb;
      }
  }
}

// ---- kv GEMM + x cast fused: BM=32, 512 blocks (2/CU, 8 waves/CU) ----
__global__ __launch_bounds__(256) void gemm_kv_cast(
    const float* __restrict__ x,            // [16384][1024] f32
    const unsigned short* __restrict__ Bw,  // kvw_bf [128][1024]
    unsigned short* __restrict__ xbf,       // [16384][1024] bf16 out
    unsigned short* __restrict__ Kout,      // [16384][64]
    unsigned short* __restrict__ VTout)     // [64][64][256]
{
  __shared__ unsigned short As[32 * 64];    // 4KB, swizzled
  __shared__ unsigned short Bs[128 * 64];   // 16KB, swizzled
  const int t = threadIdx.x;
  const int lane = t & 63, wave = t >> 6;
  const int g = lane >> 4, r = lane & 15;
  const int wr = wave >> 1, wc = wave & 1;  // wr: 16-row half; wc: K vs V
  const long row0 = (long)blockIdx.x * 32;
  const int arow = t >> 3, aq = t & 7;      // 8 lanes per row: 2 float4 each

  f32x4 acc[4] = {};

  for (int kt = 0; kt < 1024; kt += 64) {
    __syncthreads();
    const float4* src = (const float4*)(x + (row0 + arow) * 1024 + kt + aq * 8);
    float4 av0 = src[0];
    float4 av1 = src[1];
#pragma unroll
    for (int i = 0; i < 4; ++i) {
      int o = (i * 256 + t) << 4;
      int brow = o >> 7;
      int scol = (o & 127) ^ ((brow & 7) << 4);
      async16(Bw + brow * 1024 + kt + (scol >> 1), (char*)Bs + i * 4096 + wave * 1024);
    }
    u32x4 u;
    u[0] = pack_rn(av0.x, av0.y); u[1] = pack_rn(av0.z, av0.w);
    u[2] = pack_rn(av1.x, av1.y); u[3] = pack_rn(av1.z, av1.w);
    *(u32x4*)((char*)As + arow * 128 + ((aq * 16) ^ ((arow & 7) << 4))) = u;
    *(u32x4*)(xbf + (row0 + arow) * 1024 + kt + aq * 8) = u;
    __syncthreads();
#pragma unroll
    for (int ks = 0; ks < 2; ++ks) {
      int ar = wr * 16 + r;
      bf16x8 af = *(const bf16x8*)((const char*)As + ar * 128 + ((ks * 64 + g * 16) ^ ((ar & 7) << 4)));
#pragma unroll
      for (int cf = 0; cf < 4; ++cf) {
        int br = wc * 64 + cf * 16 + r;
        bf16x8 bfr = *(const bf16x8*)((const char*)Bs + br * 128 + ((ks * 64 + g * 16) ^ ((br & 7) << 4)));
        acc[cf] = __builtin_amdgcn_mfma_f32_16x16x32_bf16(af, bfr, acc[cf], 0, 0, 0);
      }
    }
  }

  if (wc == 0) {  // K part: cols 0..63
#pragma unroll
    for (int cf = 0; cf < 4; ++cf) {
      long rr = row0 + wr * 16 + g * 4;
      int cc = cf * 16 + r;
#pragma unroll
      for (int i = 0; i < 4; ++i)
        Kout[(rr + i) * 64 + cc] = f2bf(acc[cf][i]);
    }
  } else {        // V part -> transposed [w16][hd][kpos]
#pragma unroll
    for (int cf = 0; cf < 4; ++cf) {
      long tok = row0 + wr * 16 + g * 4;
      long w16 = tok >> 8;
      int kp = (int)(tok & 255);
      int hd = cf * 16 + r;
      ushort4 pk;
      pk.x = f2bf(acc[cf][0]); pk.y = f2bf(acc[cf][1]);
      pk.z = f2bf(acc[cf][2]); pk.w = f2bf(acc[cf][3]);
      *(ushort4*)(VTout + (w16 * 64 + hd) * 256 + kp) = pk;
    }
  }
}

// ---------------- windowed attention, 2 heads/block, branchless softmax ----------------
// XCD-local decode: hp = blk>>6, w16 = blk&63 -> same-window blocks share an XCD.
__global__ __launch_bounds__(512, 2) void attn_win(
    const unsigned short* __restrict__ qb,   // [16384][1024], pre-scaled
    const unsigned short* __restrict__ kb,   // [16384][64]
    const unsigned short* __restrict__ vt,   // [64 w16][64 hd][256 kpos]
    unsigned short* __restrict__ ao)         // [16384][1024]
{
  __shared__ unsigned short Ks[256 * 64];    // [kpos][hd], phi_K-swizzled
  __shared__ unsigned short Vs[64 * 256];    // V^T [hd][kpos], (hd&7)-swizzled

  const int blk = blockIdx.x;
  const int hp = blk >> 6;
  const int w16 = blk & 63;
  const long tok0 = (long)w16 * 256;
  const int t = threadIdx.x;
  const int lane = t & 63, wave = t >> 6;
  const int g = lane >> 4, r = lane & 15;
  const int h = hp * 2 + (wave >> 2);
  const int qw = wave & 3;

#pragma unroll
  for (int i = 0; i < 4; ++i) {
    int o = (i * 512 + t) << 4;
    int row = o >> 7;
    int ph = ((row & 3) << 1) | ((row >> 3) & 1);
    int scol = (o & 127) ^ (ph << 4);
    async16(kb + (tok0 + row) * 64 + (scol >> 1), (char*)Ks + i * 8192 + wave * 1024);
  }
  const unsigned short* vbase = vt + (long)w16 * (64 * 256);
#pragma unroll
  for (int i = 0; i < 4; ++i) {
    int o = (i * 512 + t) << 4;
    int hd = o >> 9;
    int scol = (o & 511) ^ ((hd & 7) << 4);
    async16(vbase + (long)hd * 256 + (scol >> 1), (char*)Vs + i * 8192 + wave * 1024);
  }

  bf16x8 qf[4][2];
#pragma unroll
  for (int cq = 0; cq < 4; ++cq)
#pragma unroll
    for (int kh = 0; kh < 2; ++kh)
      qf[cq][kh] = *(const bf16x8*)(qb + (tok0 + qw * 64 + cq * 16 + r) * 1024 + h * 64 + kh * 32 + g * 8);

  f32x4 O[4][4] = {};
  float sp[4] = {0.f, 0.f, 0.f, 0.f};
  const int rsub = 8 * (r >> 2) + (r & 3);
  __syncthreads();

#pragma unroll
  for (int kc = 0; kc < 8; ++kc) {
    f32x4 sc[2][4] = {};
#pragma unroll
    for (int kr = 0; kr < 2; ++kr) {
      int kp = kc * 32 + kr * 4 + rsub;
      int ph = ((kp & 3) << 1) | ((kp >> 3) & 1);
      bf16x8 kf0 = *(const bf16x8*)((const char*)Ks + kp * 128 + ((g * 16) ^ (ph << 4)));
      bf16x8 kf1 = *(const bf16x8*)((const char*)Ks + kp * 128 + ((64 + g * 16) ^ (ph << 4)));
      __builtin_amdgcn_s_setprio(1);
#pragma unroll
      for (int cq = 0; cq < 4; ++cq) {
        sc[kr][cq] = __builtin_amdgcn_mfma_f32_16x16x32_bf16(kf0, qf[cq][0], sc[kr][cq], 0, 0, 0);
        sc[kr][cq] = __builtin_amdgcn_mfma_f32_16x16x32_bf16(kf1, qf[cq][1], sc[kr][cq], 0, 0, 0);
      }
      __builtin_amdgcn_s_setprio(0);
    }
    bf16x8 vf[4];
#pragma unroll
    for (int ch = 0; ch < 4; ++ch) {
      int hd = ch * 16 + r;
      vf[ch] = *(const bf16x8*)((const char*)Vs + hd * 512 + ((kc * 64 + g * 16) ^ ((hd & 7) << 4)));
    }
#pragma unroll
    for (int cq = 0; cq < 4; ++cq) {
#pragma unroll
      for (int kr = 0; kr < 2; ++kr)
#pragma unroll
        for (int i = 0; i < 4; ++i)
          sc[kr][cq][i] = __builtin_amdgcn_exp2f(sc[kr][cq][i]);
      sp[cq] += ((sc[0][cq][0] + sc[0][cq][1]) + (sc[0][cq][2] + sc[0][cq][3])) +
                ((sc[1][cq][0] + sc[1][cq][1]) + (sc[1][cq][2] + sc[1][cq][3]));
    }
#pragma unroll
    for (int rq = 0; rq < 4; ++rq) {
      frag_u pa;
      pa.u[0] = pack_rn(sc[0][rq][0], sc[0][rq][1]);
      pa.u[1] = pack_rn(sc[0][rq][2], sc[0][rq][3]);
      pa.u[2] = pack_rn(sc[1][rq][0], sc[1][rq][1]);
      pa.u[3] = pack_rn(sc[1][rq][2], sc[1][rq][3]);
      __builtin_amdgcn_s_setprio(1);
#pragma unroll
      for (int ch = 0; ch < 4; ++ch)
        O[rq][ch] = __builtin_amdgcn_mfma_f32_16x16x32_bf16(pa.f, vf[ch], O[rq][ch], 0, 0, 0);
      __builtin_amdgcn_s_setprio(0);
    }
  }
  float inv[4];
#pragma unroll
  for (int cq = 0; cq < 4; ++cq) {
    float s = sp[cq];
    s += __shfl_xor(s, 16);
    s += __shfl_xor(s, 32);
    inv[cq] = 1.0f / s;
  }
#pragma unroll
  for (int rq = 0; rq < 4; ++rq)
#pragma unroll
    for (int i = 0; i < 4; ++i) {
      float w = __shfl(inv[rq], g * 4 + i);
      long tokr = tok0 + qw * 64 + rq * 16 + g * 4 + i;
#pragma unroll
      for (int ch = 0; ch < 4; ++ch)
        ao[tokr * 1024 + h * 64 + ch * 16 + r] = f2bf(O[rq][ch][i] * w);
    }
}

// ---------------- launch ----------------
extern "C" void kernel_launch(void* const* d_in, const int* in_sizes, int n_in,
                              void* d_out, int out_size, void* d_ws, size_t ws_size,
                              hipStream_t stream) {
  const float* x      = (const float*)d_in[0];
  const float* q_w    = (const float*)d_in[1];
  const float* kv_w   = (const float*)d_in[2];
  const float* proj_w = (const float*)d_in[3];
  const float* proj_b = (const float*)d_in[4];

  char* ws = (char*)d_ws;
  unsigned short* x_bf   = (unsigned short*)(ws + 0);
  unsigned short* q_bf   = (unsigned short*)(ws + 33554432);
  unsigned short* ao_bf  = (unsigned short*)(ws + 67108864);
  unsigned short* qw_bf  = (unsigned short*)(ws + 100663296);
  unsigned short* pw_bf  = (unsigned short*)(ws + 102760448);
  unsigned short* kvw_bf = (unsigned short*)(ws + 104857600);
  unsigned short* k_bf   = (unsigned short*)(ws + 105119744);
  unsigned short* vt_bf  = (unsigned short*)(ws + 107216896);
  if (ws_size < 109314048) return;

  cast_w3<<<2176, 256, 0, stream>>>(q_w, kv_w, proj_w, qw_bf, kvw_bf, pw_bf);
  gemm_kv_cast<<<512, 256, 0, stream>>>(x, kvw_bf, x_bf, k_bf, vt_bf);

  gemm256<0><<<256, 512, 0, stream>>>(x_bf, qw_bf, q_bf, nullptr, nullptr, QSCALE, 16384, 1024, 1024);
  attn_win<<<512, 512, 0, stream>>>(q_bf, k_bf, vt_bf, ao_bf);
  gemm256<1><<<256, 512, 0, stream>>>(ao_bf, pw_bf, nullptr, (float*)d_out, proj_b, 1.0f, 16384, 1024, 1024);
}

// Round 19
// 121.574 us; speedup vs baseline: 1.1544x; 1.0301x over previous
//
#include <hip/hip_runtime.h>

typedef short bf16x8 __attribute__((ext_vector_type(8)));
typedef float f32x4 __attribute__((ext_vector_type(4)));
typedef unsigned int u32x4 __attribute__((ext_vector_type(4)));

#define QSCALE 0.18033688011112042f  // 0.125 * log2(e); attention works in log2 units

__device__ __forceinline__ unsigned short f2bf(float x) {
  unsigned int u = __float_as_uint(x);
  u = (u + 0x7FFFu + ((u >> 16) & 1u)) >> 16;
  return (unsigned short)u;
}

// round-to-nearest(half-up) pack of two f32 into {lo=bf16(a), hi=bf16(b)}
__device__ __forceinline__ unsigned pack_rn(float a, float b) {
  unsigned au = __float_as_uint(a) + 0x8000u;
  unsigned bu = __float_as_uint(b) + 0x8000u;
  return (bu & 0xFFFF0000u) | (au >> 16);
}

__device__ __forceinline__ void async16(const void* g, void* l) {
  typedef const __attribute__((address_space(1))) unsigned int* gp_t;
  typedef __attribute__((address_space(3))) unsigned int* lp_t;
  __builtin_amdgcn_global_load_lds((gp_t)g, (lp_t)l, 16, 0, 0);
}

union frag_u { bf16x8 f; unsigned int u[4]; };

// one launch for the 3 weight tensors (qw | kvw | pw), float4 units
__global__ void cast_w3(const float* __restrict__ qw, const float* __restrict__ kvw,
                        const float* __restrict__ pw, unsigned short* __restrict__ qwo,
                        unsigned short* __restrict__ kvwo, unsigned short* __restrict__ pwo) {
  int i = blockIdx.x * 256 + threadIdx.x;   // 0 .. 557055
  const float* src; unsigned short* dst; int j;
  if (i < 262144)      { src = qw;  dst = qwo;  j = i; }
  else if (i < 294912) { src = kvw; dst = kvwo; j = i - 262144; }
  else                 { src = pw;  dst = pwo;  j = i - 294912; }
  float4 v = ((const float4*)src)[j];
  ushort4 o;
  o.x = f2bf(v.x); o.y = f2bf(v.y); o.z = f2bf(v.z); o.w = f2bf(v.w);
  ((ushort4*)dst)[j] = o;
}

// ============ 256x256 GEMM, C = A * B^T ============
// R8 schedule with the two hazard-free pre-MFMA barriers removed (P0, P2):
// only P1's barrier (orders all B reads before B(t+2) staging) and the
// end-of-tile vmcnt+barrier (buffer swap) remain.
// MODE 0: bf16 out (scaled by oscale). MODE 1: f32 out + bias.
template<int MODE>
__global__ __launch_bounds__(512, 2) void gemm256(
    const unsigned short* __restrict__ A,
    const unsigned short* __restrict__ Bw,
    unsigned short* __restrict__ Cbf,
    float* __restrict__ Cf,
    const float* __restrict__ bias,
    const float oscale,
    int M, int N, int K)
{
  __shared__ unsigned short S[65536];
  const int t = threadIdx.x;
  const int lane = t & 63, wave = t >> 6;
  const int g = lane >> 4, r = lane & 15;
  const int wm = wave >> 2, wn = wave & 3;

  const int nby = N >> 8;
  const int cpx = gridDim.x >> 3;
  const int bid = blockIdx.x;
  const int swz = (bid & 7) * cpx + (bid >> 3);
  const long row0 = (long)(swz / nby) * 256;
  const long col0 = (long)(swz % nby) * 256;

  const int NT = K >> 6;

  auto stage = [&](const unsigned short* gsrc, long grow0, int kcol0, int region) {
#pragma unroll
    for (int i = 0; i < 2; ++i) {
      int o = (i * 512 + t) << 4;
      int row = o >> 7;
      int scol = (o & 127) ^ ((row & 7) << 4);
      async16(gsrc + (grow0 + row) * K + kcol0 + (scol >> 1),
              (char*)S + region + i * 8192 + wave * 1024);
    }
  };
  auto ldA = [&](int bo, int ar, int ks) {
    return *(const bf16x8*)((const char*)S + bo + ar * 128 +
                            ((ks * 64 + g * 16) ^ ((ar & 7) << 4)));
  };
  auto ldB = [&](int bo, int br, int ks) {
    return *(const bf16x8*)((const char*)S + bo + 32768 + br * 128 +
                            ((ks * 64 + g * 16) ^ ((br & 7) << 4)));
  };

  f32x4 acc[8][4] = {};
  bf16x8 aF[4][2], b01[2][2], b23[2][2];

  stage(A,  row0,       0, 0);
  stage(A,  row0 + 128, 0, 16384);
  stage(Bw, col0,       0, 32768);
  stage(Bw, col0 + 128, 0, 32768 + 16384);
  if (NT > 1) {
    stage(Bw, col0,       64, 65536 + 32768);
    stage(Bw, col0 + 128, 64, 65536 + 32768 + 16384);
    asm volatile("s_waitcnt vmcnt(4)" ::: "memory");
  } else {
    asm volatile("s_waitcnt vmcnt(0)" ::: "memory");
  }
  __builtin_amdgcn_s_barrier();

  for (int kt = 0; kt < NT; ++kt) {
    const int bo = (kt & 1) << 16;
    // P0: read A(mf0-3)+B(nf0-1); stage A-half0(t+1); MFMA Q00 (no barrier)
#pragma unroll
    for (int mf = 0; mf < 4; ++mf) {
      int ar = wm * 128 + mf * 16 + r;
      aF[mf][0] = ldA(bo, ar, 0); aF[mf][1] = ldA(bo, ar, 1);
    }
#pragma unroll
    for (int nf = 0; nf < 2; ++nf) {
      int br = wn * 64 + nf * 16 + r;
      b01[nf][0] = ldB(bo, br, 0); b01[nf][1] = ldB(bo, br, 1);
    }
    if (kt + 1 < NT) stage(A, row0, (kt + 1) * 64, bo ^ 65536);
    __builtin_amdgcn_s_setprio(1);
#pragma unroll
    for (int mf = 0; mf < 4; ++mf)
#pragma unroll
      for (int nf = 0; nf < 2; ++nf) {
        acc[mf][nf] = __builtin_amdgcn_mfma_f32_16x16x32_bf16(aF[mf][0], b01[nf][0], acc[mf][nf], 0, 0, 0);
        acc[mf][nf] = __builtin_amdgcn_mfma_f32_16x16x32_bf16(aF[mf][1], b01[nf][1], acc[mf][nf], 0, 0, 0);
      }
    __builtin_amdgcn_s_setprio(0);
    // P1: read B(nf2-3); stage A-half1(t+1); BARRIER (orders all B reads); MFMA Q01
#pragma unroll
    for (int nf = 0; nf < 2; ++nf) {
      int br = wn * 64 + (nf + 2) * 16 + r;
      b23[nf][0] = ldB(bo, br, 0); b23[nf][1] = ldB(bo, br, 1);
    }
    if (kt + 1 < NT) stage(A, row0 + 128, (kt + 1) * 64, (bo ^ 65536) + 16384);
    __builtin_amdgcn_s_barrier();
    __builtin_amdgcn_s_setprio(1);
#pragma unroll
    for (int mf = 0; mf < 4; ++mf)
#pragma unroll
      for (int nf = 0; nf < 2; ++nf) {
        acc[mf][nf + 2] = __builtin_amdgcn_mfma_f32_16x16x32_bf16(aF[mf][0], b23[nf][0], acc[mf][nf + 2], 0, 0, 0);
        acc[mf][nf + 2] = __builtin_amdgcn_mfma_f32_16x16x32_bf16(aF[mf][1], b23[nf][1], acc[mf][nf + 2], 0, 0, 0);
      }
    __builtin_amdgcn_s_setprio(0);
    // P2: read A(mf4-7); stage B-half0(t+2); MFMA Q12 (no barrier)
#pragma unroll
    for (int mf = 0; mf < 4; ++mf) {
      int ar = wm * 128 + (mf + 4) * 16 + r;
      aF[mf][0] = ldA(bo, ar, 0); aF[mf][1] = ldA(bo, ar, 1);
    }
    if (kt + 2 < NT) stage(Bw, col0, (kt + 2) * 64, bo + 32768);
    __builtin_amdgcn_s_setprio(1);
#pragma unroll
    for (int mf = 0; mf < 4; ++mf)
#pragma unroll
      for (int nf = 0; nf < 2; ++nf) {
        acc[mf + 4][nf + 2] = __builtin_amdgcn_mfma_f32_16x16x32_bf16(aF[mf][0], b23[nf][0], acc[mf + 4][nf + 2], 0, 0, 0);
        acc[mf + 4][nf + 2] = __builtin_amdgcn_mfma_f32_16x16x32_bf16(aF[mf][1], b23[nf][1], acc[mf + 4][nf + 2], 0, 0, 0);
      }
    __builtin_amdgcn_s_setprio(0);
    // P4: stage B-half1(t+2); MFMA (mf4-7 x nf0-1); counted end-of-tile vmcnt
    if (kt + 2 < NT) stage(Bw, col0 + 128, (kt + 2) * 64, bo + 32768 + 16384);
    __builtin_amdgcn_s_setprio(1);
#pragma unroll
    for (int mf = 0; mf < 4; ++mf)
#pragma unroll
      for (int nf = 0; nf < 2; ++nf) {
        acc[mf + 4][nf] = __builtin_amdgcn_mfma_f32_16x16x32_bf16(aF[mf][0], b01[nf][0], acc[mf + 4][nf], 0, 0, 0);
        acc[mf + 4][nf] = __builtin_amdgcn_mfma_f32_16x16x32_bf16(aF[mf][1], b01[nf][1], acc[mf + 4][nf], 0, 0, 0);
      }
    __builtin_amdgcn_s_setprio(0);
    if (kt < NT - 2)      asm volatile("s_waitcnt vmcnt(4)" ::: "memory");
    else if (kt < NT - 1) asm volatile("s_waitcnt vmcnt(0)" ::: "memory");
    if (kt < NT - 1) __builtin_amdgcn_s_barrier();
  }

  if (MODE == 0) {
#pragma unroll
    for (int mf = 0; mf < 8; ++mf)
#pragma unroll
      for (int nf = 0; nf < 4; ++nf) {
        long rr = row0 + wm * 128 + mf * 16 + g * 4;
        long cc = col0 + wn * 64 + nf * 16 + r;
#pragma unroll
        for (int i = 0; i < 4; ++i)
          Cbf[(rr + i) * N + cc] = f2bf(acc[mf][nf][i] * oscale);
      }
  } else {
#pragma unroll
    for (int mf = 0; mf < 8; ++mf)
#pragma unroll
      for (int nf = 0; nf < 4; ++nf) {
        long rr = row0 + wm * 128 + mf * 16 + g * 4;
        long cc = col0 + wn * 64 + nf * 16 + r;
        float bb = bias[cc];
#pragma unroll
        for (int i = 0; i < 4; ++i)
          Cf[(rr + i) * N + cc] = acc[mf][nf][i] + bb;
      }
  }
}

// ---- kv GEMM + x cast fused: BM=32, 512 blocks (2/CU, 8 waves/CU) ----
__global__ __launch_bounds__(256) void gemm_kv_cast(
    const float* __restrict__ x,            // [16384][1024] f32
    const unsigned short* __restrict__ Bw,  // kvw_bf [128][1024]
    unsigned short* __restrict__ xbf,       // [16384][1024] bf16 out
    unsigned short* __restrict__ Kout,      // [16384][64]
    unsigned short* __restrict__ VTout)     // [64][64][256]
{
  __shared__ unsigned short As[32 * 64];    // 4KB, swizzled
  __shared__ unsigned short Bs[128 * 64];   // 16KB, swizzled
  const int t = threadIdx.x;
  const int lane = t & 63, wave = t >> 6;
  const int g = lane >> 4, r = lane & 15;
  const int wr = wave >> 1, wc = wave & 1;  // wr: 16-row half; wc: K vs V
  const long row0 = (long)blockIdx.x * 32;
  const int arow = t >> 3, aq = t & 7;      // 8 lanes per row: 2 float4 each

  f32x4 acc[4] = {};

  for (int kt = 0; kt < 1024; kt += 64) {
    __syncthreads();
    const float4* src = (const float4*)(x + (row0 + arow) * 1024 + kt + aq * 8);
    float4 av0 = src[0];
    float4 av1 = src[1];
#pragma unroll
    for (int i = 0; i < 4; ++i) {
      int o = (i * 256 + t) << 4;
      int brow = o >> 7;
      int scol = (o & 127) ^ ((brow & 7) << 4);
      async16(Bw + brow * 1024 + kt + (scol >> 1), (char*)Bs + i * 4096 + wave * 1024);
    }
    u32x4 u;
    u[0] = pack_rn(av0.x, av0.y); u[1] = pack_rn(av0.z, av0.w);
    u[2] = pack_rn(av1.x, av1.y); u[3] = pack_rn(av1.z, av1.w);
    *(u32x4*)((char*)As + arow * 128 + ((aq * 16) ^ ((arow & 7) << 4))) = u;
    *(u32x4*)(xbf + (row0 + arow) * 1024 + kt + aq * 8) = u;
    __syncthreads();
#pragma unroll
    for (int ks = 0; ks < 2; ++ks) {
      int ar = wr * 16 + r;
      bf16x8 af = *(const bf16x8*)((const char*)As + ar * 128 + ((ks * 64 + g * 16) ^ ((ar & 7) << 4)));
#pragma unroll
      for (int cf = 0; cf < 4; ++cf) {
        int br = wc * 64 + cf * 16 + r;
        bf16x8 bfr = *(const bf16x8*)((const char*)Bs + br * 128 + ((ks * 64 + g * 16) ^ ((br & 7) << 4)));
        acc[cf] = __builtin_amdgcn_mfma_f32_16x16x32_bf16(af, bfr, acc[cf], 0, 0, 0);
      }
    }
  }

  if (wc == 0) {  // K part: cols 0..63
#pragma unroll
    for (int cf = 0; cf < 4; ++cf) {
      long rr = row0 + wr * 16 + g * 4;
      int cc = cf * 16 + r;
#pragma unroll
      for (int i = 0; i < 4; ++i)
        Kout[(rr + i) * 64 + cc] = f2bf(acc[cf][i]);
    }
  } else {        // V part -> transposed [w16][hd][kpos]
#pragma unroll
    for (int cf = 0; cf < 4; ++cf) {
      long tok = row0 + wr * 16 + g * 4;
      long w16 = tok >> 8;
      int kp = (int)(tok & 255);
      int hd = cf * 16 + r;
      ushort4 pk;
      pk.x = f2bf(acc[cf][0]); pk.y = f2bf(acc[cf][1]);
      pk.z = f2bf(acc[cf][2]); pk.w = f2bf(acc[cf][3]);
      *(ushort4*)(VTout + (w16 * 64 + hd) * 256 + kp) = pk;
    }
  }
}

// ---------------- windowed attention, 2 heads/block, branchless softmax ----------------
// XCD-local decode: hp = blk>>6, w16 = blk&63 -> same-window blocks share an XCD.
__global__ __launch_bounds__(512, 2) void attn_win(
    const unsigned short* __restrict__ qb,   // [16384][1024], pre-scaled
    const unsigned short* __restrict__ kb,   // [16384][64]
    const unsigned short* __restrict__ vt,   // [64 w16][64 hd][256 kpos]
    unsigned short* __restrict__ ao)         // [16384][1024]
{
  __shared__ unsigned short Ks[256 * 64];    // [kpos][hd], phi_K-swizzled
  __shared__ unsigned short Vs[64 * 256];    // V^T [hd][kpos], (hd&7)-swizzled

  const int blk = blockIdx.x;
  const int hp = blk >> 6;
  const int w16 = blk & 63;
  const long tok0 = (long)w16 * 256;
  const int t = threadIdx.x;
  const int lane = t & 63, wave = t >> 6;
  const int g = lane >> 4, r = lane & 15;
  const int h = hp * 2 + (wave >> 2);
  const int qw = wave & 3;

#pragma unroll
  for (int i = 0; i < 4; ++i) {
    int o = (i * 512 + t) << 4;
    int row = o >> 7;
    int ph = ((row & 3) << 1) | ((row >> 3) & 1);
    int scol = (o & 127) ^ (ph << 4);
    async16(kb + (tok0 + row) * 64 + (scol >> 1), (char*)Ks + i * 8192 + wave * 1024);
  }
  const unsigned short* vbase = vt + (long)w16 * (64 * 256);
#pragma unroll
  for (int i = 0; i < 4; ++i) {
    int o = (i * 512 + t) << 4;
    int hd = o >> 9;
    int scol = (o & 511) ^ ((hd & 7) << 4);
    async16(vbase + (long)hd * 256 + (scol >> 1), (char*)Vs + i * 8192 + wave * 1024);
  }

  bf16x8 qf[4][2];
#pragma unroll
  for (int cq = 0; cq < 4; ++cq)
#pragma unroll
    for (int kh = 0; kh < 2; ++kh)
      qf[cq][kh] = *(const bf16x8*)(qb + (tok0 + qw * 64 + cq * 16 + r) * 1024 + h * 64 + kh * 32 + g * 8);

  f32x4 O[4][4] = {};
  float sp[4] = {0.f, 0.f, 0.f, 0.f};
  const int rsub = 8 * (r >> 2) + (r & 3);
  __syncthreads();

#pragma unroll
  for (int kc = 0; kc < 8; ++kc) {
    f32x4 sc[2][4] = {};
#pragma unroll
    for (int kr = 0; kr < 2; ++kr) {
      int kp = kc * 32 + kr * 4 + rsub;
      int ph = ((kp & 3) << 1) | ((kp >> 3) & 1);
      bf16x8 kf0 = *(const bf16x8*)((const char*)Ks + kp * 128 + ((g * 16) ^ (ph << 4)));
      bf16x8 kf1 = *(const bf16x8*)((const char*)Ks + kp * 128 + ((64 + g * 16) ^ (ph << 4)));
      __builtin_amdgcn_s_setprio(1);
#pragma unroll
      for (int cq = 0; cq < 4; ++cq) {
        sc[kr][cq] = __builtin_amdgcn_mfma_f32_16x16x32_bf16(kf0, qf[cq][0], sc[kr][cq], 0, 0, 0);
        sc[kr][cq] = __builtin_amdgcn_mfma_f32_16x16x32_bf16(kf1, qf[cq][1], sc[kr][cq], 0, 0, 0);
      }
      __builtin_amdgcn_s_setprio(0);
    }
    bf16x8 vf[4];
#pragma unroll
    for (int ch = 0; ch < 4; ++ch) {
      int hd = ch * 16 + r;
      vf[ch] = *(const bf16x8*)((const char*)Vs + hd * 512 + ((kc * 64 + g * 16) ^ ((hd & 7) << 4)));
    }
#pragma unroll
    for (int cq = 0; cq < 4; ++cq) {
#pragma unroll
      for (int kr = 0; kr < 2; ++kr)
#pragma unroll
        for (int i = 0; i < 4; ++i)
          sc[kr][cq][i] = __builtin_amdgcn_exp2f(sc[kr][cq][i]);
      sp[cq] += ((sc[0][cq][0] + sc[0][cq][1]) + (sc[0][cq][2] + sc[0][cq][3])) +
                ((sc[1][cq][0] + sc[1][cq][1]) + (sc[1][cq][2] + sc[1][cq][3]));
    }
#pragma unroll
    for (int rq = 0; rq < 4; ++rq) {
      frag_u pa;
      pa.u[0] = pack_rn(sc[0][rq][0], sc[0][rq][1]);
      pa.u[1] = pack_rn(sc[0][rq][2], sc[0][rq][3]);
      pa.u[2] = pack_rn(sc[1][rq][0], sc[1][rq][1]);
      pa.u[3] = pack_rn(sc[1][rq][2], sc[1][rq][3]);
      __builtin_amdgcn_s_setprio(1);
#pragma unroll
      for (int ch = 0; ch < 4; ++ch)
        O[rq][ch] = __builtin_amdgcn_mfma_f32_16x16x32_bf16(pa.f, vf[ch], O[rq][ch], 0, 0, 0);
      __builtin_amdgcn_s_setprio(0);
    }
  }
  float inv[4];
#pragma unroll
  for (int cq = 0; cq < 4; ++cq) {
    float s = sp[cq];
    s += __shfl_xor(s, 16);
    s += __shfl_xor(s, 32);
    inv[cq] = 1.0f / s;
  }
#pragma unroll
  for (int rq = 0; rq < 4; ++rq)
#pragma unroll
    for (int i = 0; i < 4; ++i) {
      float w = __shfl(inv[rq], g * 4 + i);
      long tokr = tok0 + qw * 64 + rq * 16 + g * 4 + i;
#pragma unroll
      for (int ch = 0; ch < 4; ++ch)
        ao[tokr * 1024 + h * 64 + ch * 16 + r] = f2bf(O[rq][ch][i] * w);
    }
}

// ---------------- launch ----------------
extern "C" void kernel_launch(void* const* d_in, const int* in_sizes, int n_in,
                              void* d_out, int out_size, void* d_ws, size_t ws_size,
                              hipStream_t stream) {
  const float* x      = (const float*)d_in[0];
  const float* q_w    = (const float*)d_in[1];
  const float* kv_w   = (const float*)d_in[2];
  const float* proj_w = (const float*)d_in[3];
  const float* proj_b = (const float*)d_in[4];

  char* ws = (char*)d_ws;
  unsigned short* x_bf   = (unsigned short*)(ws + 0);
  unsigned short* q_bf   = (unsigned short*)(ws + 33554432);
  unsigned short* ao_bf  = (unsigned short*)(ws + 67108864);
  unsigned short* qw_bf  = (unsigned short*)(ws + 100663296);
  unsigned short* pw_bf  = (unsigned short*)(ws + 102760448);
  unsigned short* kvw_bf = (unsigned short*)(ws + 104857600);
  unsigned short* k_bf   = (unsigned short*)(ws + 105119744);
  unsigned short* vt_bf  = (unsigned short*)(ws + 107216896);
  if (ws_size < 109314048) return;

  cast_w3<<<2176, 256, 0, stream>>>(q_w, kv_w, proj_w, qw_bf, kvw_bf, pw_bf);
  gemm_kv_cast<<<512, 256, 0, stream>>>(x, kvw_bf, x_bf, k_bf, vt_bf);

  gemm256<0><<<256, 512, 0, stream>>>(x_bf, qw_bf, q_bf, nullptr, nullptr, QSCALE, 16384, 1024, 1024);
  attn_win<<<512, 512, 0, stream>>>(q_bf, k_bf, vt_bf, ao_bf);
  gemm256<1><<<256, 512, 0, stream>>>(ao_bf, pw_bf, nullptr, (float*)d_out, proj_b, 1.0f, 16384, 1024, 1024);
}

// Round 20
// 121.272 us; speedup vs baseline: 1.1572x; 1.0025x over previous
//
#include <hip/hip_runtime.h>

typedef short bf16x8 __attribute__((ext_vector_type(8)));
typedef float f32x4 __attribute__((ext_vector_type(4)));
typedef unsigned int u32x4 __attribute__((ext_vector_type(4)));

#define QSCALE 0.18033688011112042f  // 0.125 * log2(e); attention works in log2 units

__device__ __forceinline__ unsigned short f2bf(float x) {
  unsigned int u = __float_as_uint(x);
  u = (u + 0x7FFFu + ((u >> 16) & 1u)) >> 16;
  return (unsigned short)u;
}

// round-to-nearest(half-up) pack of two f32 into {lo=bf16(a), hi=bf16(b)}
__device__ __forceinline__ unsigned pack_rn(float a, float b) {
  unsigned au = __float_as_uint(a) + 0x8000u;
  unsigned bu = __float_as_uint(b) + 0x8000u;
  return (bu & 0xFFFF0000u) | (au >> 16);
}

__device__ __forceinline__ void async16(const void* g, void* l) {
  typedef const __attribute__((address_space(1))) unsigned int* gp_t;
  typedef __attribute__((address_space(3))) unsigned int* lp_t;
  __builtin_amdgcn_global_load_lds((gp_t)g, (lp_t)l, 16, 0, 0);
}

union frag_u { bf16x8 f; unsigned int u[4]; };

// qw | kvw casts (pw is cast inside gemm256<0>'s prologue stall)
__global__ void cast_w2(const float* __restrict__ qw, const float* __restrict__ kvw,
                        unsigned short* __restrict__ qwo, unsigned short* __restrict__ kvwo) {
  int i = blockIdx.x * 256 + threadIdx.x;   // 0 .. 294911
  const float* src; unsigned short* dst; int j;
  if (i < 262144)      { src = qw;  dst = qwo;  j = i; }
  else                 { src = kvw; dst = kvwo; j = i - 262144; }
  float4 v = ((const float4*)src)[j];
  ushort4 o;
  o.x = f2bf(v.x); o.y = f2bf(v.y); o.z = f2bf(v.z); o.w = f2bf(v.w);
  ((ushort4*)dst)[j] = o;
}

// ============ 256x256 GEMM, C = A * B^T (R19 schedule: 2 barriers/K-tile) ============
// MODE 0: bf16 out (scaled by oscale) + pw f32->bf16 cast hidden in prologue.
// MODE 1: f32 out + bias.
template<int MODE>
__global__ __launch_bounds__(512, 2) void gemm256(
    const unsigned short* __restrict__ A,
    const unsigned short* __restrict__ Bw,
    unsigned short* __restrict__ Cbf,
    float* __restrict__ Cf,
    const float* __restrict__ bias,
    const float* __restrict__ pwsrc,
    unsigned short* __restrict__ pwdst,
    const float oscale,
    int M, int N, int K)
{
  __shared__ unsigned short S[65536];
  const int t = threadIdx.x;
  const int lane = t & 63, wave = t >> 6;
  const int g = lane >> 4, r = lane & 15;
  const int wm = wave >> 2, wn = wave & 3;

  const int nby = N >> 8;
  const int cpx = gridDim.x >> 3;
  const int bid = blockIdx.x;
  const int swz = (bid & 7) * cpx + (bid >> 3);
  const long row0 = (long)(swz / nby) * 256;
  const long col0 = (long)(swz % nby) * 256;

  const int NT = K >> 6;

  // MODE 0: cast this block's slice of proj_w (2 float4/thread), issued FIRST so
  // these VMEM ops sit at the FIFO head — all later counted vmcnt waits stay safe.
  if (MODE == 0) {
    int j0 = bid * 1024 + t;
    float4 v0 = ((const float4*)pwsrc)[j0];
    float4 v1 = ((const float4*)pwsrc)[j0 + 512];
    u32x4 u0;
    u0[0] = pack_rn(v0.x, v0.y); u0[1] = pack_rn(v0.z, v0.w);
    u0[2] = pack_rn(v1.x, v1.y); u0[3] = pack_rn(v1.z, v1.w);
    ((unsigned int*)pwdst)[j0 * 2]       = u0[0];
    ((unsigned int*)pwdst)[j0 * 2 + 1]   = u0[1];
    ((unsigned int*)pwdst)[(j0 + 512) * 2]     = u0[2];
    ((unsigned int*)pwdst)[(j0 + 512) * 2 + 1] = u0[3];
  }

  auto stage = [&](const unsigned short* gsrc, long grow0, int kcol0, int region) {
#pragma unroll
    for (int i = 0; i < 2; ++i) {
      int o = (i * 512 + t) << 4;
      int row = o >> 7;
      int scol = (o & 127) ^ ((row & 7) << 4);
      async16(gsrc + (grow0 + row) * K + kcol0 + (scol >> 1),
              (char*)S + region + i * 8192 + wave * 1024);
    }
  };
  auto ldA = [&](int bo, int ar, int ks) {
    return *(const bf16x8*)((const char*)S + bo + ar * 128 +
                            ((ks * 64 + g * 16) ^ ((ar & 7) << 4)));
  };
  auto ldB = [&](int bo, int br, int ks) {
    return *(const bf16x8*)((const char*)S + bo + 32768 + br * 128 +
                            ((ks * 64 + g * 16) ^ ((br & 7) << 4)));
  };

  f32x4 acc[8][4] = {};
  bf16x8 aF[4][2], b01[2][2], b23[2][2];

  stage(A,  row0,       0, 0);
  stage(A,  row0 + 128, 0, 16384);
  stage(Bw, col0,       0, 32768);
  stage(Bw, col0 + 128, 0, 32768 + 16384);
  if (NT > 1) {
    stage(Bw, col0,       64, 65536 + 32768);
    stage(Bw, col0 + 128, 64, 65536 + 32768 + 16384);
    asm volatile("s_waitcnt vmcnt(4)" ::: "memory");
  } else {
    asm volatile("s_waitcnt vmcnt(0)" ::: "memory");
  }
  __builtin_amdgcn_s_barrier();

  for (int kt = 0; kt < NT; ++kt) {
    const int bo = (kt & 1) << 16;
    // P0: read A(mf0-3)+B(nf0-1); stage A-half0(t+1); MFMA Q00 (no barrier)
#pragma unroll
    for (int mf = 0; mf < 4; ++mf) {
      int ar = wm * 128 + mf * 16 + r;
      aF[mf][0] = ldA(bo, ar, 0); aF[mf][1] = ldA(bo, ar, 1);
    }
#pragma unroll
    for (int nf = 0; nf < 2; ++nf) {
      int br = wn * 64 + nf * 16 + r;
      b01[nf][0] = ldB(bo, br, 0); b01[nf][1] = ldB(bo, br, 1);
    }
    if (kt + 1 < NT) stage(A, row0, (kt + 1) * 64, bo ^ 65536);
    __builtin_amdgcn_s_setprio(1);
#pragma unroll
    for (int mf = 0; mf < 4; ++mf)
#pragma unroll
      for (int nf = 0; nf < 2; ++nf) {
        acc[mf][nf] = __builtin_amdgcn_mfma_f32_16x16x32_bf16(aF[mf][0], b01[nf][0], acc[mf][nf], 0, 0, 0);
        acc[mf][nf] = __builtin_amdgcn_mfma_f32_16x16x32_bf16(aF[mf][1], b01[nf][1], acc[mf][nf], 0, 0, 0);
      }
    __builtin_amdgcn_s_setprio(0);
    // P1: read B(nf2-3); stage A-half1(t+1); BARRIER (orders all B reads); MFMA Q01
#pragma unroll
    for (int nf = 0; nf < 2; ++nf) {
      int br = wn * 64 + (nf + 2) * 16 + r;
      b23[nf][0] = ldB(bo, br, 0); b23[nf][1] = ldB(bo, br, 1);
    }
    if (kt + 1 < NT) stage(A, row0 + 128, (kt + 1) * 64, (bo ^ 65536) + 16384);
    __builtin_amdgcn_s_barrier();
    __builtin_amdgcn_s_setprio(1);
#pragma unroll
    for (int mf = 0; mf < 4; ++mf)
#pragma unroll
      for (int nf = 0; nf < 2; ++nf) {
        acc[mf][nf + 2] = __builtin_amdgcn_mfma_f32_16x16x32_bf16(aF[mf][0], b23[nf][0], acc[mf][nf + 2], 0, 0, 0);
        acc[mf][nf + 2] = __builtin_amdgcn_mfma_f32_16x16x32_bf16(aF[mf][1], b23[nf][1], acc[mf][nf + 2], 0, 0, 0);
      }
    __builtin_amdgcn_s_setprio(0);
    // P2: read A(mf4-7); stage B-half0(t+2); MFMA Q12 (no barrier)
#pragma unroll
    for (int mf = 0; mf < 4; ++mf) {
      int ar = wm * 128 + (mf + 4) * 16 + r;
      aF[mf][0] = ldA(bo, ar, 0); aF[mf][1] = ldA(bo, ar, 1);
    }
    if (kt + 2 < NT) stage(Bw, col0, (kt + 2) * 64, bo + 32768);
    __builtin_amdgcn_s_setprio(1);
#pragma unroll
    for (int mf = 0; mf < 4; ++mf)
#pragma unroll
      for (int nf = 0; nf < 2; ++nf) {
        acc[mf + 4][nf + 2] = __builtin_amdgcn_mfma_f32_16x16x32_bf16(aF[mf][0], b23[nf][0], acc[mf + 4][nf + 2], 0, 0, 0);
        acc[mf + 4][nf + 2] = __builtin_amdgcn_mfma_f32_16x16x32_bf16(aF[mf][1], b23[nf][1], acc[mf + 4][nf + 2], 0, 0, 0);
      }
    __builtin_amdgcn_s_setprio(0);
    // P4: stage B-half1(t+2); MFMA (mf4-7 x nf0-1); counted end-of-tile vmcnt
    if (kt + 2 < NT) stage(Bw, col0 + 128, (kt + 2) * 64, bo + 32768 + 16384);
    __builtin_amdgcn_s_setprio(1);
#pragma unroll
    for (int mf = 0; mf < 4; ++mf)
#pragma unroll
      for (int nf = 0; nf < 2; ++nf) {
        acc[mf + 4][nf] = __builtin_amdgcn_mfma_f32_16x16x32_bf16(aF[mf][0], b01[nf][0], acc[mf + 4][nf], 0, 0, 0);
        acc[mf + 4][nf] = __builtin_amdgcn_mfma_f32_16x16x32_bf16(aF[mf][1], b01[nf][1], acc[mf + 4][nf], 0, 0, 0);
      }
    __builtin_amdgcn_s_setprio(0);
    if (kt < NT - 2)      asm volatile("s_waitcnt vmcnt(4)" ::: "memory");
    else if (kt < NT - 1) asm volatile("s_waitcnt vmcnt(0)" ::: "memory");
    if (kt < NT - 1) __builtin_amdgcn_s_barrier();
  }

  if (MODE == 0) {
#pragma unroll
    for (int mf = 0; mf < 8; ++mf)
#pragma unroll
      for (int nf = 0; nf < 4; ++nf) {
        long rr = row0 + wm * 128 + mf * 16 + g * 4;
        long cc = col0 + wn * 64 + nf * 16 + r;
#pragma unroll
        for (int i = 0; i < 4; ++i)
          Cbf[(rr + i) * N + cc] = f2bf(acc[mf][nf][i] * oscale);
      }
  } else {
#pragma unroll
    for (int mf = 0; mf < 8; ++mf)
#pragma unroll
      for (int nf = 0; nf < 4; ++nf) {
        long rr = row0 + wm * 128 + mf * 16 + g * 4;
        long cc = col0 + wn * 64 + nf * 16 + r;
        float bb = bias[cc];
#pragma unroll
        for (int i = 0; i < 4; ++i)
          Cf[(rr + i) * N + cc] = acc[mf][nf][i] + bb;
      }
  }
}

// ---- kv GEMM + x cast fused: BM=32, 512 blocks (2/CU, 8 waves/CU) ----
__global__ __launch_bounds__(256) void gemm_kv_cast(
    const float* __restrict__ x,            // [16384][1024] f32
    const unsigned short* __restrict__ Bw,  // kvw_bf [128][1024]
    unsigned short* __restrict__ xbf,       // [16384][1024] bf16 out
    unsigned short* __restrict__ Kout,      // [16384][64]
    unsigned short* __restrict__ VTout)     // [64][64][256]
{
  __shared__ unsigned short As[32 * 64];    // 4KB, swizzled
  __shared__ unsigned short Bs[128 * 64];   // 16KB, swizzled
  const int t = threadIdx.x;
  const int lane = t & 63, wave = t >> 6;
  const int g = lane >> 4, r = lane & 15;
  const int wr = wave >> 1, wc = wave & 1;  // wr: 16-row half; wc: K vs V
  const long row0 = (long)blockIdx.x * 32;
  const int arow = t >> 3, aq = t & 7;      // 8 lanes per row: 2 float4 each

  f32x4 acc[4] = {};

  for (int kt = 0; kt < 1024; kt += 64) {
    __syncthreads();
    const float4* src = (const float4*)(x + (row0 + arow) * 1024 + kt + aq * 8);
    float4 av0 = src[0];
    float4 av1 = src[1];
#pragma unroll
    for (int i = 0; i < 4; ++i) {
      int o = (i * 256 + t) << 4;
      int brow = o >> 7;
      int scol = (o & 127) ^ ((brow & 7) << 4);
      async16(Bw + brow * 1024 + kt + (scol >> 1), (char*)Bs + i * 4096 + wave * 1024);
    }
    u32x4 u;
    u[0] = pack_rn(av0.x, av0.y); u[1] = pack_rn(av0.z, av0.w);
    u[2] = pack_rn(av1.x, av1.y); u[3] = pack_rn(av1.z, av1.w);
    *(u32x4*)((char*)As + arow * 128 + ((aq * 16) ^ ((arow & 7) << 4))) = u;
    *(u32x4*)(xbf + (row0 + arow) * 1024 + kt + aq * 8) = u;
    __syncthreads();
#pragma unroll
    for (int ks = 0; ks < 2; ++ks) {
      int ar = wr * 16 + r;
      bf16x8 af = *(const bf16x8*)((const char*)As + ar * 128 + ((ks * 64 + g * 16) ^ ((ar & 7) << 4)));
#pragma unroll
      for (int cf = 0; cf < 4; ++cf) {
        int br = wc * 64 + cf * 16 + r;
        bf16x8 bfr = *(const bf16x8*)((const char*)Bs + br * 128 + ((ks * 64 + g * 16) ^ ((br & 7) << 4)));
        acc[cf] = __builtin_amdgcn_mfma_f32_16x16x32_bf16(af, bfr, acc[cf], 0, 0, 0);
      }
    }
  }

  if (wc == 0) {  // K part: cols 0..63
#pragma unroll
    for (int cf = 0; cf < 4; ++cf) {
      long rr = row0 + wr * 16 + g * 4;
      int cc = cf * 16 + r;
#pragma unroll
      for (int i = 0; i < 4; ++i)
        Kout[(rr + i) * 64 + cc] = f2bf(acc[cf][i]);
    }
  } else {        // V part -> transposed [w16][hd][kpos]
#pragma unroll
    for (int cf = 0; cf < 4; ++cf) {
      long tok = row0 + wr * 16 + g * 4;
      long w16 = tok >> 8;
      int kp = (int)(tok & 255);
      int hd = cf * 16 + r;
      ushort4 pk;
      pk.x = f2bf(acc[cf][0]); pk.y = f2bf(acc[cf][1]);
      pk.z = f2bf(acc[cf][2]); pk.w = f2bf(acc[cf][3]);
      *(ushort4*)(VTout + (w16 * 64 + hd) * 256 + kp) = pk;
    }
  }
}

// ---------------- windowed attention, 2 heads/block, branchless softmax ----------------
// XCD-local decode: hp = blk>>6, w16 = blk&63 -> same-window blocks share an XCD.
__global__ __launch_bounds__(512, 2) void attn_win(
    const unsigned short* __restrict__ qb,   // [16384][1024], pre-scaled
    const unsigned short* __restrict__ kb,   // [16384][64]
    const unsigned short* __restrict__ vt,   // [64 w16][64 hd][256 kpos]
    unsigned short* __restrict__ ao)         // [16384][1024]
{
  __shared__ unsigned short Ks[256 * 64];    // [kpos][hd], phi_K-swizzled
  __shared__ unsigned short Vs[64 * 256];    // V^T [hd][kpos], (hd&7)-swizzled

  const int blk = blockIdx.x;
  const int hp = blk >> 6;
  const int w16 = blk & 63;
  const long tok0 = (long)w16 * 256;
  const int t = threadIdx.x;
  const int lane = t & 63, wave = t >> 6;
  const int g = lane >> 4, r = lane & 15;
  const int h = hp * 2 + (wave >> 2);
  const int qw = wave & 3;

#pragma unroll
  for (int i = 0; i < 4; ++i) {
    int o = (i * 512 + t) << 4;
    int row = o >> 7;
    int ph = ((row & 3) << 1) | ((row >> 3) & 1);
    int scol = (o & 127) ^ (ph << 4);
    async16(kb + (tok0 + row) * 64 + (scol >> 1), (char*)Ks + i * 8192 + wave * 1024);
  }
  const unsigned short* vbase = vt + (long)w16 * (64 * 256);
#pragma unroll
  for (int i = 0; i < 4; ++i) {
    int o = (i * 512 + t) << 4;
    int hd = o >> 9;
    int scol = (o & 511) ^ ((hd & 7) << 4);
    async16(vbase + (long)hd * 256 + (scol >> 1), (char*)Vs + i * 8192 + wave * 1024);
  }

  bf16x8 qf[4][2];
#pragma unroll
  for (int cq = 0; cq < 4; ++cq)
#pragma unroll
    for (int kh = 0; kh < 2; ++kh)
      qf[cq][kh] = *(const bf16x8*)(qb + (tok0 + qw * 64 + cq * 16 + r) * 1024 + h * 64 + kh * 32 + g * 8);

  f32x4 O[4][4] = {};
  float sp[4] = {0.f, 0.f, 0.f, 0.f};
  const int rsub = 8 * (r >> 2) + (r & 3);
  __syncthreads();

#pragma unroll
  for (int kc = 0; kc < 8; ++kc) {
    f32x4 sc[2][4] = {};
#pragma unroll
    for (int kr = 0; kr < 2; ++kr) {
      int kp = kc * 32 + kr * 4 + rsub;
      int ph = ((kp & 3) << 1) | ((kp >> 3) & 1);
      bf16x8 kf0 = *(const bf16x8*)((const char*)Ks + kp * 128 + ((g * 16) ^ (ph << 4)));
      bf16x8 kf1 = *(const bf16x8*)((const char*)Ks + kp * 128 + ((64 + g * 16) ^ (ph << 4)));
      __builtin_amdgcn_s_setprio(1);
#pragma unroll
      for (int cq = 0; cq < 4; ++cq) {
        sc[kr][cq] = __builtin_amdgcn_mfma_f32_16x16x32_bf16(kf0, qf[cq][0], sc[kr][cq], 0, 0, 0);
        sc[kr][cq] = __builtin_amdgcn_mfma_f32_16x16x32_bf16(kf1, qf[cq][1], sc[kr][cq], 0, 0, 0);
      }
      __builtin_amdgcn_s_setprio(0);
    }
    bf16x8 vf[4];
#pragma unroll
    for (int ch = 0; ch < 4; ++ch) {
      int hd = ch * 16 + r;
      vf[ch] = *(const bf16x8*)((const char*)Vs + hd * 512 + ((kc * 64 + g * 16) ^ ((hd & 7) << 4)));
    }
#pragma unroll
    for (int cq = 0; cq < 4; ++cq) {
#pragma unroll
      for (int kr = 0; kr < 2; ++kr)
#pragma unroll
        for (int i = 0; i < 4; ++i)
          sc[kr][cq][i] = __builtin_amdgcn_exp2f(sc[kr][cq][i]);
      sp[cq] += ((sc[0][cq][0] + sc[0][cq][1]) + (sc[0][cq][2] + sc[0][cq][3])) +
                ((sc[1][cq][0] + sc[1][cq][1]) + (sc[1][cq][2] + sc[1][cq][3]));
    }
#pragma unroll
    for (int rq = 0; rq < 4; ++rq) {
      frag_u pa;
      pa.u[0] = pack_rn(sc[0][rq][0], sc[0][rq][1]);
      pa.u[1] = pack_rn(sc[0][rq][2], sc[0][rq][3]);
      pa.u[2] = pack_rn(sc[1][rq][0], sc[1][rq][1]);
      pa.u[3] = pack_rn(sc[1][rq][2], sc[1][rq][3]);
      __builtin_amdgcn_s_setprio(1);
#pragma unroll
      for (int ch = 0; ch < 4; ++ch)
        O[rq][ch] = __builtin_amdgcn_mfma_f32_16x16x32_bf16(pa.f, vf[ch], O[rq][ch], 0, 0, 0);
      __builtin_amdgcn_s_setprio(0);
    }
  }
  float inv[4];
#pragma unroll
  for (int cq = 0; cq < 4; ++cq) {
    float s = sp[cq];
    s += __shfl_xor(s, 16);
    s += __shfl_xor(s, 32);
    inv[cq] = 1.0f / s;
  }
#pragma unroll
  for (int rq = 0; rq < 4; ++rq)
#pragma unroll
    for (int i = 0; i < 4; ++i) {
      float w = __shfl(inv[rq], g * 4 + i);
      long tokr = tok0 + qw * 64 + rq * 16 + g * 4 + i;
#pragma unroll
      for (int ch = 0; ch < 4; ++ch)
        ao[tokr * 1024 + h * 64 + ch * 16 + r] = f2bf(O[rq][ch][i] * w);
    }
}

// ---------------- launch ----------------
extern "C" void kernel_launch(void* const* d_in, const int* in_sizes, int n_in,
                              void* d_out, int out_size, void* d_ws, size_t ws_size,
                              hipStream_t stream) {
  const float* x      = (const float*)d_in[0];
  const float* q_w    = (const float*)d_in[1];
  const float* kv_w   = (const float*)d_in[2];
  const float* proj_w = (const float*)d_in[3];
  const float* proj_b = (const float*)d_in[4];

  char* ws = (char*)d_ws;
  unsigned short* x_bf   = (unsigned short*)(ws + 0);
  unsigned short* q_bf   = (unsigned short*)(ws + 33554432);
  unsigned short* ao_bf  = (unsigned short*)(ws + 67108864);
  unsigned short* qw_bf  = (unsigned short*)(ws + 100663296);
  unsigned short* pw_bf  = (unsigned short*)(ws + 102760448);
  unsigned short* kvw_bf = (unsigned short*)(ws + 104857600);
  unsigned short* k_bf   = (unsigned short*)(ws + 105119744);
  unsigned short* vt_bf  = (unsigned short*)(ws + 107216896);
  if (ws_size < 109314048) return;

  cast_w2<<<1152, 256, 0, stream>>>(q_w, kv_w, qw_bf, kvw_bf);
  gemm_kv_cast<<<512, 256, 0, stream>>>(x, kvw_bf, x_bf, k_bf, vt_bf);

  gemm256<0><<<256, 512, 0, stream>>>(x_bf, qw_bf, q_bf, nullptr, nullptr,
                                      proj_w, pw_bf, QSCALE, 16384, 1024, 1024);
  attn_win<<<512, 512, 0, stream>>>(q_bf, k_bf, vt_bf, ao_bf);
  gemm256<1><<<256, 512, 0, stream>>>(ao_bf, pw_bf, nullptr, (float*)d_out, proj_b,
                                      nullptr, nullptr, 1.0f, 16384, 1024, 1024);
}